// Round 1
// 1875.911 us; speedup vs baseline: 1.0469x; 1.0469x over previous
//
#include <hip/hip_runtime.h>
#include <hip/hip_bf16.h>
#include <math.h>

#define T_TOK 16384
#define H_DIM 1024
#define I_DIM 2048
#define E_NUM 16
#define MAX_TILES 272   // sum_e ceil(cnt_e/128) <= (32768 + 16*127)/128 < 272

typedef short bf16x8 __attribute__((ext_vector_type(8)));
typedef float f32x4 __attribute__((ext_vector_type(4)));

// ---------------- workspace layout (bytes) ----------------
static constexpr size_t XB_BYTES  = (size_t)T_TOK * H_DIM * 2;                // 32 MB
static constexpr size_t WC_BYTES  = (size_t)E_NUM * 2 * I_DIM * H_DIM * 2;    // 128 MB  [E][2I][H] interleaved gate/up
static constexpr size_t WD_BYTES  = (size_t)E_NUM * H_DIM * I_DIM * 2;        // 64 MB   [E][H][I]
static constexpr size_t HB_BYTES  = (size_t)2 * T_TOK * I_DIM * 2;            // 128 MB
static constexpr size_t LIST_BYTES= (size_t)E_NUM * T_TOK * 4;                // 1 MB

static constexpr size_t XB_OFF    = 0;
static constexpr size_t WC_OFF    = XB_OFF + XB_BYTES;
static constexpr size_t WDT_OFF   = WC_OFF + WC_BYTES;
static constexpr size_t HB_OFF    = WDT_OFF + WD_BYTES;
static constexpr size_t ROWS_OFF  = HB_OFF + HB_BYTES;
static constexpr size_t WTS_OFF   = ROWS_OFF + LIST_BYTES;
static constexpr size_t CNT_OFF   = WTS_OFF + LIST_BYTES;
static constexpr size_t BASE_OFF  = CNT_OFF + 256;
static constexpr size_t TILES_OFF = BASE_OFF + 256;
static constexpr size_t NT_OFF    = TILES_OFF + 2048;

// ---------------- async global->LDS 16B helper ----------------
__device__ __forceinline__ void async_ld16(void* lds, const void* g) {
    __builtin_amdgcn_global_load_lds(
        (const __attribute__((address_space(1))) void*)g,
        (__attribute__((address_space(3))) void*)lds,
        16, 0, 0);
}

// in: [E][R][C] fp32 -> out: [E][Nd][R] bf16 (B^T layout).
// Column mapping: ioff < 0 -> n = c (plain transpose, Nd == C)
//                 ioff >= 0 -> n = 32*(c>>4) + ioff + (c&15)  (16-col interleave, Nd == 2C)
__global__ void transpose_convert_kernel(const float* __restrict__ in,
                                         __hip_bfloat16* __restrict__ out,
                                         int R, int C, int Nd, int ioff) {
    __shared__ float tile[32][33];
    int e = blockIdx.z;
    int c0 = blockIdx.x * 32;
    int r0 = blockIdx.y * 32;
    const float* pin = in + (size_t)e * R * C;
    __hip_bfloat16* pout = out + (size_t)e * Nd * R;
    int tx = threadIdx.x, ty = threadIdx.y;   // block (32,8)
    #pragma unroll
    for (int j = 0; j < 4; j++)
        tile[ty + j*8][tx] = pin[(size_t)(r0 + ty + j*8) * C + (c0 + tx)];
    __syncthreads();
    #pragma unroll
    for (int j = 0; j < 4; j++) {
        int c = c0 + ty + j*8;
        int n = (ioff < 0) ? c : 32*(c >> 4) + ioff + (c & 15);
        pout[(size_t)n * R + (r0 + tx)] = __float2bfloat16(tile[tx][ty + j*8]);
    }
}

// ---------------- router: fp64 logits, top-2, renorm, list build + x->bf16 ----------------
__global__ void router_kernel(const float* __restrict__ x, const float* __restrict__ wg,
                              int* __restrict__ cnt, int* __restrict__ rows,
                              float* __restrict__ wts, __hip_bfloat16* __restrict__ xb) {
    int t = blockIdx.x;
    int lane = threadIdx.x;   // 64 threads = 1 wave
    float xv[16];
    const float* xp = x + (size_t)t * H_DIM;
    __hip_bfloat16* xbp = xb + (size_t)t * H_DIM;
    #pragma unroll
    for (int j = 0; j < 16; j++) xv[j] = xp[j*64 + lane];
    // fold in the fp32->bf16 conversion (saves a separate pass over x)
    #pragma unroll
    for (int j = 0; j < 16; j++) xbp[j*64 + lane] = __float2bfloat16(xv[j]);
    double logits[E_NUM];
    #pragma unroll
    for (int e = 0; e < E_NUM; e++) {
        double p = 0.0;
        #pragma unroll
        for (int j = 0; j < 16; j++)
            p += (double)xv[j] * (double)wg[(j*64 + lane) * E_NUM + e];
        #pragma unroll
        for (int off = 32; off > 0; off >>= 1) p += __shfl_down(p, off);
        logits[e] = p;
    }
    if (lane == 0) {
        int i1 = 0; double v1 = logits[0];
        #pragma unroll
        for (int e = 1; e < E_NUM; e++) if (logits[e] > v1) { v1 = logits[e]; i1 = e; }
        int i2 = -1; double v2 = -1e300;
        #pragma unroll
        for (int e = 0; e < E_NUM; e++) if (e != i1 && logits[e] > v2) { v2 = logits[e]; i2 = e; }
        double w1 = 1.0 / (1.0 + exp(v2 - v1));
        float w1f = (float)w1, w2f = (float)(1.0 - w1);
        int s1 = atomicAdd(&cnt[i1], 1);
        rows[i1 * T_TOK + s1] = t; wts[i1 * T_TOK + s1] = w1f;
        int s2 = atomicAdd(&cnt[i2], 1);
        rows[i2 * T_TOK + s2] = t; wts[i2 * T_TOK + s2] = w2f;
    }
}

// ---------------- schedule: exclusive scan + tile descriptors ----------------
__global__ void schedule_kernel(const int* __restrict__ cnt, int* __restrict__ base,
                                int* __restrict__ tiles, int* __restrict__ ntiles) {
    int b = 0, nt = 0;
    for (int e = 0; e < E_NUM; e++) {
        base[e] = b;
        int c = cnt[e];
        int m = (c + 127) >> 7;
        for (int i = 0; i < m; i++) tiles[nt++] = (e << 16) | i;
        b += c;
    }
    ntiles[0] = nt;
}

// ---------------- unified grouped-GEMM template (double-buffered 2-phase) ----------------
// MODE 0: fused gate+up — A = xb (token gather), B = Wcomb [E][2I][H] (16-col interleave);
//         epilogue: hbuf[row][i] = u * silu(g), g = acc[.][2p], u = acc[.][2p+1]
// MODE 2: down — A = hbuf (contiguous), B = Wdt [E][H][I]; atomicAdd(out[token], wt*acc)
// LDS: chunk-major [8][128][8] (conflict-free, wave-uniform-base for global_load_lds),
// double-buffered (2 x 16 KB per matrix = 64 KB total).
// K-loop: prefetch buf[cur^1] BEFORE computing buf[cur]; single barrier per iteration —
// staging latency hides under ds_read+MFMA (T3-minimum schedule).
template<int MODE>
__global__ __launch_bounds__(256) void moe_gemm_kernel(
    const __hip_bfloat16* __restrict__ Abase,
    const __hip_bfloat16* __restrict__ Bw,
    void* __restrict__ Cout,
    const int* __restrict__ rows, const float* __restrict__ wts,
    const int* __restrict__ cnt, const int* __restrict__ base,
    const int* __restrict__ tiles, const int* __restrict__ ntiles,
    int Kd, int Nd)
{
    if ((int)blockIdx.y >= ntiles[0]) return;
    int td = tiles[blockIdx.y];
    int e = td >> 16, tile = td & 0xffff;
    int cnt_e = cnt[e], base_e = base[e];
    int cnt_local = cnt_e - tile * 128;
    int bn = blockIdx.x;
    const int* rows_e = rows + e * T_TOK;
    const __hip_bfloat16* Be = Bw + (size_t)e * Nd * Kd;

    __shared__ __align__(16) __hip_bfloat16 As[2][8][128][8];
    __shared__ __align__(16) __hip_bfloat16 Bs[2][8][128][8];

    int tid = threadIdx.x;
    int w = tid >> 6, lane = tid & 63;

    // staging slots: unit u = w*4+j covers LDS bytes [u*1024, u*1024+1024)
    const __hip_bfloat16* aptr[4];
    const __hip_bfloat16* bptr[4];
    uint32_t loff[4];
    #pragma unroll
    for (int j = 0; j < 4; j++) {
        int u = w * 4 + j;
        int chunk = u >> 1, half = u & 1;
        int r = half * 64 + lane;
        int gr = tile * 128 + r;
        size_t arow;
        if (MODE == 2) {
            int rr = base_e + gr;
            if (rr > 2 * T_TOK - 1) rr = 2 * T_TOK - 1;
            arow = (size_t)rr;
        } else {
            arow = (size_t)((gr < cnt_e) ? rows_e[gr] : 0);
        }
        aptr[j] = Abase + arow * Kd + chunk * 8;
        bptr[j] = Be + (size_t)(bn * 128 + r) * Kd + chunk * 8;
        loff[j] = (uint32_t)(u * 1024);
    }

    int wm = w >> 1, wn = w & 1;
    int l16 = lane & 15, quad = lane >> 4;

    f32x4 acc[4][4];
    #pragma unroll
    for (int a = 0; a < 4; a++)
        #pragma unroll
        for (int b = 0; b < 4; b++) acc[a][b] = (f32x4){0.f, 0.f, 0.f, 0.f};

    char* AsB = (char*)&As[0][0][0][0];
    char* BsB = (char*)&Bs[0][0][0][0];

    // prologue: stage K-tile 0 into buffer 0
    #pragma unroll
    for (int j = 0; j < 4; j++) {
        async_ld16(AsB + loff[j], aptr[j]);
        async_ld16(BsB + loff[j], bptr[j]);
        aptr[j] += 64; bptr[j] += 64;
    }
    __syncthreads();   // drains vmcnt: buffer 0 ready

    int nk = Kd >> 6;
    int cur = 0;
    for (int k0 = 0; k0 < nk; ++k0) {
        // issue next K-tile's loads into the other buffer (stay in flight
        // across the MFMA phase; drained by the barrier below)
        if (k0 + 1 < nk) {
            int nxt = cur ^ 1;
            #pragma unroll
            for (int j = 0; j < 4; j++) {
                async_ld16(AsB + nxt * 16384 + loff[j], aptr[j]);
                async_ld16(BsB + nxt * 16384 + loff[j], bptr[j]);
                aptr[j] += 64; bptr[j] += 64;
            }
        }
        #pragma unroll
        for (int ks = 0; ks < 2; ks++) {
            bf16x8 af[4], bfr[4];
            #pragma unroll
            for (int mt = 0; mt < 4; mt++)
                af[mt] = *(const bf16x8*)&As[cur][ks*4 + quad][wm*64 + mt*16 + l16][0];
            #pragma unroll
            for (int nt = 0; nt < 4; nt++)
                bfr[nt] = *(const bf16x8*)&Bs[cur][ks*4 + quad][wn*64 + nt*16 + l16][0];
            #pragma unroll
            for (int mt = 0; mt < 4; mt++)
                #pragma unroll
                for (int nt = 0; nt < 4; nt++)
                    acc[mt][nt] = __builtin_amdgcn_mfma_f32_16x16x32_bf16(af[mt], bfr[nt], acc[mt][nt], 0, 0, 0);
        }
        // one barrier per iteration: all waves done reading buf[cur]
        // (lgkmcnt drain) AND next buffer's loads landed (vmcnt drain)
        __syncthreads();
        cur ^= 1;
    }

    // epilogue: C/D layout col=lane&15, row=quad*4+r (m89-verified)
    #pragma unroll
    for (int mt = 0; mt < 4; mt++) {
        #pragma unroll
        for (int r = 0; r < 4; r++) {
            int row = wm*64 + mt*16 + quad*4 + r;
            if (row < cnt_local) {
                int gr = tile * 128 + row;
                if (MODE == 0) {
                    // interleaved cols: n = 32*j + t*16 + c  ->  i = 16*j + c
                    // acc[mt][2p] = gate, acc[mt][2p+1] = up for the same i
                    __hip_bfloat16* hp = (__hip_bfloat16*)Cout + (size_t)(base_e + gr) * I_DIM;
                    #pragma unroll
                    for (int p = 0; p < 2; p++) {
                        int icol = (bn*4 + wn*2 + p)*16 + l16;
                        float g = acc[mt][2*p][r];
                        float u = acc[mt][2*p+1][r];
                        hp[icol] = __float2bfloat16(u * (g / (1.f + expf(-g))));
                    }
                } else {
                    int token = rows_e[gr];
                    float wt = (wts + e * T_TOK)[gr];
                    float* op = (float*)Cout + (size_t)token * H_DIM + bn*128 + wn*64;
                    #pragma unroll
                    for (int nt = 0; nt < 4; nt++)
                        atomicAdd(op + nt*16 + l16, wt * acc[mt][nt][r]);
                }
            }
        }
    }
}

// ---------------- launch ----------------
extern "C" void kernel_launch(void* const* d_in, const int* in_sizes, int n_in,
                              void* d_out, int out_size, void* d_ws, size_t ws_size,
                              hipStream_t stream) {
    const float* x   = (const float*)d_in[0];
    const float* wg  = (const float*)d_in[1];
    const float* wgp = (const float*)d_in[2];
    const float* wup = (const float*)d_in[3];
    const float* wdp = (const float*)d_in[4];
    float* out = (float*)d_out;
    char* ws = (char*)d_ws;

    __hip_bfloat16* xb   = (__hip_bfloat16*)(ws + XB_OFF);
    __hip_bfloat16* Wc   = (__hip_bfloat16*)(ws + WC_OFF);
    __hip_bfloat16* Wdt  = (__hip_bfloat16*)(ws + WDT_OFF);
    __hip_bfloat16* hbuf = (__hip_bfloat16*)(ws + HB_OFF);
    int*   rowsp  = (int*)(ws + ROWS_OFF);
    float* wtsp   = (float*)(ws + WTS_OFF);
    int*   cntp   = (int*)(ws + CNT_OFF);
    int*   basep  = (int*)(ws + BASE_OFF);
    int*   tilesp = (int*)(ws + TILES_OFF);
    int*   ntp    = (int*)(ws + NT_OFF);

    hipMemsetAsync(cntp, 0, 256, stream);
    hipMemsetAsync(out, 0, (size_t)out_size * sizeof(float), stream);

    // gate weights -> even 16-col groups, up weights -> odd 16-col groups of Wc [E][2I][H]
    transpose_convert_kernel<<<dim3(I_DIM/32, H_DIM/32, E_NUM), dim3(32, 8), 0, stream>>>(
        wgp, Wc, H_DIM, I_DIM, 2*I_DIM, 0);
    transpose_convert_kernel<<<dim3(I_DIM/32, H_DIM/32, E_NUM), dim3(32, 8), 0, stream>>>(
        wup, Wc, H_DIM, I_DIM, 2*I_DIM, 16);
    transpose_convert_kernel<<<dim3(H_DIM/32, I_DIM/32, E_NUM), dim3(32, 8), 0, stream>>>(
        wdp, Wdt, I_DIM, H_DIM, H_DIM, -1);
    router_kernel<<<T_TOK, 64, 0, stream>>>(x, wg, cntp, rowsp, wtsp, xb);
    schedule_kernel<<<1, 1, 0, stream>>>(cntp, basep, tilesp, ntp);

    // fused gate+up: hbuf = u * silu(g)
    moe_gemm_kernel<0><<<dim3(2*I_DIM/128, MAX_TILES), 256, 0, stream>>>(
        xb, Wc, hbuf, rowsp, wtsp, cntp, basep, tilesp, ntp, H_DIM, 2*I_DIM);
    // down + weighted scatter
    moe_gemm_kernel<2><<<dim3(H_DIM/128, MAX_TILES), 256, 0, stream>>>(
        hbuf, Wdt, out, rowsp, wtsp, cntp, basep, tilesp, ntp, I_DIM, H_DIM);
}

// Round 2
// 1780.640 us; speedup vs baseline: 1.1029x; 1.0535x over previous
//
#include <hip/hip_runtime.h>
#include <hip/hip_bf16.h>
#include <math.h>

#define T_TOK 16384
#define H_DIM 1024
#define I_DIM 2048
#define E_NUM 16
#define MAX_TILES 144   // sum_e ceil(cnt_e/256) <= (32768 + 16*255)/256 < 144

typedef short bf16x8 __attribute__((ext_vector_type(8)));
typedef float f32x4 __attribute__((ext_vector_type(4)));

// ---------------- workspace layout (bytes) ----------------
static constexpr size_t XB_BYTES  = (size_t)T_TOK * H_DIM * 2;                // 32 MB
static constexpr size_t WC_BYTES  = (size_t)E_NUM * 2 * I_DIM * H_DIM * 2;    // 128 MB  [E][2I][H] interleaved gate/up
static constexpr size_t WD_BYTES  = (size_t)E_NUM * H_DIM * I_DIM * 2;        // 64 MB   [E][H][I]
static constexpr size_t HB_BYTES  = (size_t)2 * T_TOK * I_DIM * 2;            // 128 MB
static constexpr size_t LIST_BYTES= (size_t)E_NUM * T_TOK * 4;                // 1 MB

static constexpr size_t XB_OFF    = 0;
static constexpr size_t WC_OFF    = XB_OFF + XB_BYTES;
static constexpr size_t WDT_OFF   = WC_OFF + WC_BYTES;
static constexpr size_t HB_OFF    = WDT_OFF + WD_BYTES;
static constexpr size_t ROWS_OFF  = HB_OFF + HB_BYTES;
static constexpr size_t WTS_OFF   = ROWS_OFF + LIST_BYTES;
static constexpr size_t CNT_OFF   = WTS_OFF + LIST_BYTES;
static constexpr size_t BASE_OFF  = CNT_OFF + 256;
static constexpr size_t TILES_OFF = BASE_OFF + 256;
static constexpr size_t NT_OFF    = TILES_OFF + 2048;

// ---------------- async global->LDS 16B helper ----------------
__device__ __forceinline__ void async_ld16(void* lds, const void* g) {
    __builtin_amdgcn_global_load_lds(
        (const __attribute__((address_space(1))) void*)g,
        (__attribute__((address_space(3))) void*)lds,
        16, 0, 0);
}

// in: [E][R][C] fp32 -> out: [E][Nd][R] bf16 (B^T layout).
// Column mapping: ioff < 0 -> n = c (plain transpose, Nd == C)
//                 ioff >= 0 -> n = 32*(c>>4) + ioff + (c&15)  (16-col interleave, Nd == 2C)
__global__ void transpose_convert_kernel(const float* __restrict__ in,
                                         __hip_bfloat16* __restrict__ out,
                                         int R, int C, int Nd, int ioff) {
    __shared__ float tile[32][33];
    int e = blockIdx.z;
    int c0 = blockIdx.x * 32;
    int r0 = blockIdx.y * 32;
    const float* pin = in + (size_t)e * R * C;
    __hip_bfloat16* pout = out + (size_t)e * Nd * R;
    int tx = threadIdx.x, ty = threadIdx.y;   // block (32,8)
    #pragma unroll
    for (int j = 0; j < 4; j++)
        tile[ty + j*8][tx] = pin[(size_t)(r0 + ty + j*8) * C + (c0 + tx)];
    __syncthreads();
    #pragma unroll
    for (int j = 0; j < 4; j++) {
        int c = c0 + ty + j*8;
        int n = (ioff < 0) ? c : 32*(c >> 4) + ioff + (c & 15);
        pout[(size_t)n * R + (r0 + tx)] = __float2bfloat16(tile[tx][ty + j*8]);
    }
}

// ---------------- router: fp64 logits, top-2, renorm, list build + x->bf16 ----------------
__global__ void router_kernel(const float* __restrict__ x, const float* __restrict__ wg,
                              int* __restrict__ cnt, int* __restrict__ rows,
                              float* __restrict__ wts, __hip_bfloat16* __restrict__ xb) {
    int t = blockIdx.x;
    int lane = threadIdx.x;   // 64 threads = 1 wave
    float xv[16];
    const float* xp = x + (size_t)t * H_DIM;
    __hip_bfloat16* xbp = xb + (size_t)t * H_DIM;
    #pragma unroll
    for (int j = 0; j < 16; j++) xv[j] = xp[j*64 + lane];
    #pragma unroll
    for (int j = 0; j < 16; j++) xbp[j*64 + lane] = __float2bfloat16(xv[j]);
    double logits[E_NUM];
    #pragma unroll
    for (int e = 0; e < E_NUM; e++) {
        double p = 0.0;
        #pragma unroll
        for (int j = 0; j < 16; j++)
            p += (double)xv[j] * (double)wg[(j*64 + lane) * E_NUM + e];
        #pragma unroll
        for (int off = 32; off > 0; off >>= 1) p += __shfl_down(p, off);
        logits[e] = p;
    }
    if (lane == 0) {
        int i1 = 0; double v1 = logits[0];
        #pragma unroll
        for (int e = 1; e < E_NUM; e++) if (logits[e] > v1) { v1 = logits[e]; i1 = e; }
        int i2 = -1; double v2 = -1e300;
        #pragma unroll
        for (int e = 0; e < E_NUM; e++) if (e != i1 && logits[e] > v2) { v2 = logits[e]; i2 = e; }
        double w1 = 1.0 / (1.0 + exp(v2 - v1));
        float w1f = (float)w1, w2f = (float)(1.0 - w1);
        int s1 = atomicAdd(&cnt[i1], 1);
        rows[i1 * T_TOK + s1] = t; wts[i1 * T_TOK + s1] = w1f;
        int s2 = atomicAdd(&cnt[i2], 1);
        rows[i2 * T_TOK + s2] = t; wts[i2 * T_TOK + s2] = w2f;
    }
}

// ---------------- schedule: wave-parallel scan + tile descriptors (256-row tiles) ----------------
__global__ void schedule_kernel(const int* __restrict__ cnt, int* __restrict__ base,
                                int* __restrict__ tiles, int* __restrict__ ntiles) {
    int lane = threadIdx.x;   // 64 threads = 1 wave; only lanes 0..15 carry data
    int c = (lane < E_NUM) ? cnt[lane] : 0;
    int m = (c + 255) >> 8;
    int b = c, t = m;
    #pragma unroll
    for (int off = 1; off < 16; off <<= 1) {
        int vb = __shfl_up(b, off);
        int vt = __shfl_up(t, off);
        if ((lane & 15) >= off) { b += vb; t += vt; }
    }
    int bex = b - c, tex = t - m;   // exclusive scans
    if (lane < E_NUM) {
        base[lane] = bex;
        for (int i = 0; i < m; i++) tiles[tex + i] = (lane << 16) | i;
        if (lane == E_NUM - 1) ntiles[0] = tex + m;
    }
}

// ---------------- unified grouped-GEMM, 256x256 tile, 8 waves, double-buffered 2-phase ----
// MODE 0: fused gate+up — A = xb (token gather), B = Wcomb [E][2I][H] (16-col interleave);
//         epilogue: hbuf[row][i] = u * silu(g)
// MODE 2: down — A = hbuf (contiguous), B = Wdt [E][H][I]; atomicAdd(out[token], wt*acc)
// LDS: chunk-major [8][256][8] per matrix per buffer (conflict-free ds_read_b128,
// wave-uniform-base staging); 2 x (32KB A + 32KB B) = 128 KB.
// Wave grid 2M x 4N; per-wave output 128x64 (acc 8x4 f32x4) — m201 geometry.
template<int MODE>
__global__ __launch_bounds__(512) void moe_gemm_kernel(
    const __hip_bfloat16* __restrict__ Abase,
    const __hip_bfloat16* __restrict__ Bw,
    void* __restrict__ Cout,
    const int* __restrict__ rows, const float* __restrict__ wts,
    const int* __restrict__ cnt, const int* __restrict__ base,
    const int* __restrict__ tiles, const int* __restrict__ ntiles,
    int Kd, int Nd)
{
    if ((int)blockIdx.y >= ntiles[0]) return;
    int td = tiles[blockIdx.y];
    int e = td >> 16, tile = td & 0xffff;
    int cnt_e = cnt[e], base_e = base[e];
    int cnt_local = cnt_e - tile * 256;
    int bn = blockIdx.x;
    const int* rows_e = rows + e * T_TOK;
    const __hip_bfloat16* Be = Bw + (size_t)e * Nd * Kd;

    __shared__ __align__(16) __hip_bfloat16 As[2][8][256][8];
    __shared__ __align__(16) __hip_bfloat16 Bs[2][8][256][8];

    int tid = threadIdx.x;
    int w = tid >> 6, lane = tid & 63;    // 8 waves

    // staging: unit u = w*4+j covers LDS bytes [u*1024, u*1024+1024)
    // = chunk (u>>2), rows (u&3)*64 + lane; HW writes lane*16 past base
    const __hip_bfloat16* aptr[4];
    const __hip_bfloat16* bptr[4];
    uint32_t loff[4];
    #pragma unroll
    for (int j = 0; j < 4; j++) {
        int u = w * 4 + j;
        int chunk = u >> 2, quarter = u & 3;
        int r = quarter * 64 + lane;
        int gr = tile * 256 + r;
        size_t arow;
        if (MODE == 2) {
            int rr = base_e + gr;
            if (rr > 2 * T_TOK - 1) rr = 2 * T_TOK - 1;
            arow = (size_t)rr;
        } else {
            arow = (size_t)((gr < cnt_e) ? rows_e[gr] : 0);
        }
        aptr[j] = Abase + arow * Kd + chunk * 8;
        bptr[j] = Be + (size_t)(bn * 256 + r) * Kd + chunk * 8;
        loff[j] = (uint32_t)(u * 1024);
    }

    int wm = w >> 2, wn = w & 3;          // 2M x 4N wave grid
    int l16 = lane & 15, quad = lane >> 4;

    f32x4 acc[8][4];
    #pragma unroll
    for (int a = 0; a < 8; a++)
        #pragma unroll
        for (int b = 0; b < 4; b++) acc[a][b] = (f32x4){0.f, 0.f, 0.f, 0.f};

    char* AsB = (char*)&As[0][0][0][0];
    char* BsB = (char*)&Bs[0][0][0][0];

    // prologue: stage K-tile 0 into buffer 0
    #pragma unroll
    for (int j = 0; j < 4; j++) {
        async_ld16(AsB + loff[j], aptr[j]);
        async_ld16(BsB + loff[j], bptr[j]);
        aptr[j] += 64; bptr[j] += 64;
    }
    __syncthreads();   // drains vmcnt: buffer 0 ready

    int nk = Kd >> 6;
    int cur = 0;
    for (int k0 = 0; k0 < nk; ++k0) {
        if (k0 + 1 < nk) {
            int nxt = cur ^ 1;
            #pragma unroll
            for (int j = 0; j < 4; j++) {
                async_ld16(AsB + nxt * 32768 + loff[j], aptr[j]);
                async_ld16(BsB + nxt * 32768 + loff[j], bptr[j]);
                aptr[j] += 64; bptr[j] += 64;
            }
        }
        #pragma unroll
        for (int ks = 0; ks < 2; ks++) {
            bf16x8 af[8], bfr[4];
            #pragma unroll
            for (int nt = 0; nt < 4; nt++)
                bfr[nt] = *(const bf16x8*)&Bs[cur][ks*4 + quad][wn*64 + nt*16 + l16][0];
            #pragma unroll
            for (int mt = 0; mt < 8; mt++)
                af[mt] = *(const bf16x8*)&As[cur][ks*4 + quad][wm*128 + mt*16 + l16][0];
            #pragma unroll
            for (int mt = 0; mt < 8; mt++)
                #pragma unroll
                for (int nt = 0; nt < 4; nt++)
                    acc[mt][nt] = __builtin_amdgcn_mfma_f32_16x16x32_bf16(af[mt], bfr[nt], acc[mt][nt], 0, 0, 0);
        }
        __syncthreads();  // all reads of buf[cur] done AND buf[nxt] loads landed
        cur ^= 1;
    }

    // epilogue: C/D layout col=lane&15, row=quad*4+r (m89-verified)
    #pragma unroll
    for (int mt = 0; mt < 8; mt++) {
        #pragma unroll
        for (int r = 0; r < 4; r++) {
            int row = wm*128 + mt*16 + quad*4 + r;
            if (row < cnt_local) {
                int gr = tile * 256 + row;
                if (MODE == 0) {
                    // interleaved cols: acc[mt][2p]=gate, acc[mt][2p+1]=up for i-col
                    __hip_bfloat16* hp = (__hip_bfloat16*)Cout + (size_t)(base_e + gr) * I_DIM;
                    #pragma unroll
                    for (int p = 0; p < 2; p++) {
                        int icol = (bn*8 + wn*2 + p)*16 + l16;
                        float g = acc[mt][2*p][r];
                        float u = acc[mt][2*p+1][r];
                        hp[icol] = __float2bfloat16(u * (g / (1.f + expf(-g))));
                    }
                } else {
                    int token = rows_e[gr];
                    float wt = (wts + e * T_TOK)[gr];
                    float* op = (float*)Cout + (size_t)token * H_DIM + bn*256 + wn*64;
                    #pragma unroll
                    for (int nt = 0; nt < 4; nt++)
                        atomicAdd(op + nt*16 + l16, wt * acc[mt][nt][r]);
                }
            }
        }
    }
}

// ---------------- launch ----------------
extern "C" void kernel_launch(void* const* d_in, const int* in_sizes, int n_in,
                              void* d_out, int out_size, void* d_ws, size_t ws_size,
                              hipStream_t stream) {
    const float* x   = (const float*)d_in[0];
    const float* wg  = (const float*)d_in[1];
    const float* wgp = (const float*)d_in[2];
    const float* wup = (const float*)d_in[3];
    const float* wdp = (const float*)d_in[4];
    float* out = (float*)d_out;
    char* ws = (char*)d_ws;

    __hip_bfloat16* xb   = (__hip_bfloat16*)(ws + XB_OFF);
    __hip_bfloat16* Wc   = (__hip_bfloat16*)(ws + WC_OFF);
    __hip_bfloat16* Wdt  = (__hip_bfloat16*)(ws + WDT_OFF);
    __hip_bfloat16* hbuf = (__hip_bfloat16*)(ws + HB_OFF);
    int*   rowsp  = (int*)(ws + ROWS_OFF);
    float* wtsp   = (float*)(ws + WTS_OFF);
    int*   cntp   = (int*)(ws + CNT_OFF);
    int*   basep  = (int*)(ws + BASE_OFF);
    int*   tilesp = (int*)(ws + TILES_OFF);
    int*   ntp    = (int*)(ws + NT_OFF);

    hipMemsetAsync(cntp, 0, 256, stream);
    hipMemsetAsync(out, 0, (size_t)out_size * sizeof(float), stream);

    // gate weights -> even 16-col groups, up weights -> odd 16-col groups of Wc [E][2I][H]
    transpose_convert_kernel<<<dim3(I_DIM/32, H_DIM/32, E_NUM), dim3(32, 8), 0, stream>>>(
        wgp, Wc, H_DIM, I_DIM, 2*I_DIM, 0);
    transpose_convert_kernel<<<dim3(I_DIM/32, H_DIM/32, E_NUM), dim3(32, 8), 0, stream>>>(
        wup, Wc, H_DIM, I_DIM, 2*I_DIM, 16);
    transpose_convert_kernel<<<dim3(H_DIM/32, I_DIM/32, E_NUM), dim3(32, 8), 0, stream>>>(
        wdp, Wdt, I_DIM, H_DIM, H_DIM, -1);
    router_kernel<<<T_TOK, 64, 0, stream>>>(x, wg, cntp, rowsp, wtsp, xb);
    schedule_kernel<<<1, 64, 0, stream>>>(cntp, basep, tilesp, ntp);

    // fused gate+up: hbuf = u * silu(g)
    moe_gemm_kernel<0><<<dim3(2*I_DIM/256, MAX_TILES), 512, 0, stream>>>(
        xb, Wc, hbuf, rowsp, wtsp, cntp, basep, tilesp, ntp, H_DIM, 2*I_DIM);
    // down + weighted scatter
    moe_gemm_kernel<2><<<dim3(H_DIM/256, MAX_TILES), 512, 0, stream>>>(
        hbuf, Wdt, out, rowsp, wtsp, cntp, basep, tilesp, ntp, I_DIM, H_DIM);
}